// Round 3
// baseline (231.437 us; speedup 1.0000x reference)
//
#include <hip/hip_runtime.h>

// SpikingLayer: T=64 sequential steps over [B=32, F=16384] fp32 state.
//   state = (x + state) - act
//   state = max(state + 1.0f, 0.0f) - 1.0f   // bit-exact relu(s+1)-1, NOT max(s,-1)
//   act   = state > 0 ? floor(state) : 0
// 134 MB in + 134 MB out => ~43 us floor @ 6.3 TB/s.
//
// R2 lesson: 8 waves/CU + depth-2 prefetch = latency-bound at 1.2 TB/s.
// This version: 1 chain/thread (524288 threads, 32 waves/CU) + 8-deep
// prefetch ring => ~64 KB outstanding loads per CU, ~16 MB machine-wide.

#define T_STEPS 64
#define NCHAINS (32 * 16384)   // 524288 independent chains, one per thread
#define PF 8                   // prefetch depth (register ring)

__global__ __launch_bounds__(256, 8) void spiking_kernel(
    const float* __restrict__ in, float* __restrict__ out) {
    const int i = blockIdx.x * blockDim.x + threadIdx.x;

    float s = 0.f, a = 0.f;
    float xs[PF];

    // prime the ring: 8 loads in flight before any compute
    #pragma unroll
    for (int j = 0; j < PF; ++j) xs[j] = in[j * NCHAINS + i];

    // fully unrolled: t%PF and the prefetch guard are compile-time static,
    // so the ring is pure register renaming (no dynamic indexing)
    #pragma unroll
    for (int t = 0; t < T_STEPS; ++t) {
        float x = xs[t % PF];
        if (t + PF < T_STEPS) xs[t % PF] = in[(t + PF) * NCHAINS + i];

        s = (x + s) - a;                    // membrane update (ref op order)
        s = fmaxf(s + 1.0f, 0.0f) - 1.0f;   // relu(s - thr_low) + thr_low, bit-exact
        a = (s > 0.0f) ? floorf(s) : 0.0f;  // spike count

        out[t * NCHAINS + i] = a;
    }
}

extern "C" void kernel_launch(void* const* d_in, const int* in_sizes, int n_in,
                              void* d_out, int out_size, void* d_ws, size_t ws_size,
                              hipStream_t stream) {
    const float* in = (const float*)d_in[0];
    float* out = (float*)d_out;
    // 524288 threads / 256 = 2048 blocks -> 8 blocks/CU, 32 waves/CU
    spiking_kernel<<<NCHAINS / 256, 256, 0, stream>>>(in, out);
}

// Round 6
// 217.649 us; speedup vs baseline: 1.0634x; 1.0634x over previous
//
#include <hip/hip_runtime.h>

// SpikingLayer: T=64 sequential steps over [B=32, F=16384] fp32 state.
//   state = (x + state) - act
//   state = max(state + 1.0f, 0.0f) - 1.0f   // bit-exact relu(s+1)-1, NOT max(s,-1)
//   act   = state > 0 ? floor(state) : 0
// 134 MB in + 134 MB out => ~31-43 us floor.
//
// R2: float4, depth-2, 8 waves/CU  -> ~71 us
// R3: scalar, depth-8, 32 waves/CU -> ~82 us  (more MLP, slower!)
// Lesson: vmem instruction efficiency (1 KB/instr) beats raw occupancy.
// R6: float4 + depth-8 ring (64 KB/CU in flight) + nontemporal hints so the
// 131 MB output stream doesn't evict the input stream from L2/L3.
// (R4/R5 compile fixes: clang ext_vector for the builtin; scalar float[4]
// for state since refs can't bind to vector elements.)

#define T_STEPS 64
#define NCHAINS (32 * 16384)       // B*F = 524288 independent chains
#define NCHAINS4 (NCHAINS / 4)     // float4 groups: 131072 threads
#define PF 8                       // prefetch ring depth (float4 -> 8 KB/wave)

typedef float vfloat4 __attribute__((ext_vector_type(4)));

__device__ __forceinline__ float step1(float x, float& s) {
    // returns new activation; updates state in place
    s = fmaxf(s + x + 1.0f, 0.0f) - 1.0f;   // see note below
    float a = (s > 0.0f) ? floorf(s) : 0.0f;
    return a;
}

__global__ __launch_bounds__(256) void spiking_kernel(
    const vfloat4* __restrict__ in, vfloat4* __restrict__ out) {
    const int i = blockIdx.x * blockDim.x + threadIdx.x;

    float s[4] = {0.f, 0.f, 0.f, 0.f};
    float a[4] = {0.f, 0.f, 0.f, 0.f};

    vfloat4 xs[PF];
    // prime the ring: 8 KB/wave in flight before any compute
    #pragma unroll
    for (int j = 0; j < PF; ++j)
        xs[j] = __builtin_nontemporal_load(&in[j * NCHAINS4 + i]);

    // fully unrolled: ring index + guard are compile-time static
    #pragma unroll
    for (int t = 0; t < T_STEPS; ++t) {
        vfloat4 x = xs[t % PF];
        if (t + PF < T_STEPS)
            xs[t % PF] = __builtin_nontemporal_load(&in[(t + PF) * NCHAINS4 + i]);

        float xe[4] = {x.x, x.y, x.z, x.w};
        #pragma unroll
        for (int e = 0; e < 4; ++e) {
            // EXACT ref op order: s = (x + s) - a; s = max(s+1,0)-1; a = spikes
            float sv = (xe[e] + s[e]) - a[e];
            sv = fmaxf(sv + 1.0f, 0.0f) - 1.0f;
            s[e] = sv;
            a[e] = (sv > 0.0f) ? floorf(sv) : 0.0f;
        }

        vfloat4 av = {a[0], a[1], a[2], a[3]};
        __builtin_nontemporal_store(av, &out[t * NCHAINS4 + i]);
    }
}

extern "C" void kernel_launch(void* const* d_in, const int* in_sizes, int n_in,
                              void* d_out, int out_size, void* d_ws, size_t ws_size,
                              hipStream_t stream) {
    const vfloat4* in = (const vfloat4*)d_in[0];
    vfloat4* out = (vfloat4*)d_out;
    // 131072 threads / 256 = 512 blocks -> 2 blocks/CU, 8 waves/CU
    spiking_kernel<<<NCHAINS4 / 256, 256, 0, stream>>>(in, out);
}